// Round 2
// baseline (213.463 us; speedup 1.0000x reference)
//
#include <hip/hip_runtime.h>

// AWQ int4 GEMM: out[64,11008](f32) = x[64,4096](f32) @ dequant(qweight) + bias
// qweight [K, N/8] int32 AWQ nibble order; qzeros [G, N/8] int32; scales [G, N] f32;
// group size 128 (G=32). Reference tensors are fp16 -> harness delivers float32.

#define KD   4096
#define ND   11008
#define NPW  1376      // ND/8
#define BN   64        // n-columns per block

using frag_ab = __attribute__((ext_vector_type(8))) short;   // 8 bf16 = 4 VGPR
using f32x4   = __attribute__((ext_vector_type(4))) float;
using bf16x8  = __attribute__((ext_vector_type(8))) __bf16;

__device__ __forceinline__ frag_ab pack_bf16(f32x4 a, f32x4 b) {
    bf16x8 r;
    r[0] = (__bf16)a[0]; r[1] = (__bf16)a[1]; r[2] = (__bf16)a[2]; r[3] = (__bf16)a[3];
    r[4] = (__bf16)b[0]; r[5] = (__bf16)b[1]; r[6] = (__bf16)b[2]; r[7] = (__bf16)b[3];
    return __builtin_bit_cast(frag_ab, r);
}

__global__ __launch_bounds__(256) void awq_gemm(
    const float* __restrict__ x,
    const int*   __restrict__ qw,
    const float* __restrict__ sc,
    const int*   __restrict__ qz,
    const float* __restrict__ bias,
    float*       __restrict__ out)
{
    const int tid  = threadIdx.x;
    const int wv   = tid >> 6;        // wave 0..3 -> n-tile
    const int lane = tid & 63;
    const int l15  = lane & 15;
    const int q4   = lane >> 4;       // quad 0..3

    // This lane's output/B column
    const int n   = blockIdx.x * BN + wv * 16 + l15;
    const int npw = n >> 3;
    // AWQ: logical col i within pack sits at nibble ((i&1)<<2)|(i>>1)
    const int sh  = ((((n & 1) << 2) | ((n & 7) >> 1)) << 2);

    const int*   qwp = qw + npw;           // row k at qwp[k*NPW]
    const float* xp  = x + l15 * KD;       // + mt*16*KD + k

    f32x4 acc[4] = {};   // 4 m-tiles x 4 f32

    // ---- software-pipelined k loop (one step of prefetch) ----
    int   w_pf[8];
    f32x4 a_pf[4][2];
    {
        const int kb = q4 * 8;   // k0 = 0
        #pragma unroll
        for (int j = 0; j < 8; ++j) w_pf[j] = qwp[(kb + j) * NPW];
        #pragma unroll
        for (int mt = 0; mt < 4; ++mt) {
            a_pf[mt][0] = *(const f32x4*)(xp + mt * 16 * KD + kb);
            a_pf[mt][1] = *(const f32x4*)(xp + mt * 16 * KD + kb + 4);
        }
    }

    float s_f = 0.f, z_f = 0.f;
    for (int k0 = 0; k0 < KD; k0 += 32) {
        // group scale/zero (uniform branch; every 4th iteration)
        if ((k0 & 127) == 0) {
            const int g = k0 >> 7;
            s_f = sc[g * ND + n];
            const int z = (qz[g * NPW + npw] >> sh) & 0xF;
            z_f = -s_f * (float)z;    // exact in f32
        }

        // take current stage
        int   w_c[8];
        f32x4 a_c[4][2];
        #pragma unroll
        for (int j = 0; j < 8; ++j)  w_c[j] = w_pf[j];
        #pragma unroll
        for (int mt = 0; mt < 4; ++mt) {
            a_c[mt][0] = a_pf[mt][0];
            a_c[mt][1] = a_pf[mt][1];
        }

        // prefetch next k-step
        const int k1 = k0 + 32;
        if (k1 < KD) {
            const int kb = k1 + q4 * 8;
            #pragma unroll
            for (int j = 0; j < 8; ++j) w_pf[j] = qwp[(kb + j) * NPW];
            #pragma unroll
            for (int mt = 0; mt < 4; ++mt) {
                a_pf[mt][0] = *(const f32x4*)(xp + mt * 16 * KD + kb);
                a_pf[mt][1] = *(const f32x4*)(xp + mt * 16 * KD + kb + 4);
            }
        }

        // dequant this lane's B fragment: 8 k-elements of column n
        // (q - z)*s == fma(q, s, -z*s), exact in f32, one RNE cvt to bf16
        bf16x8 bb;
        #pragma unroll
        for (int j = 0; j < 8; ++j) {
            const float f = fmaf((float)((w_c[j] >> sh) & 0xF), s_f, z_f);
            bb[j] = (__bf16)f;
        }
        const frag_ab b = __builtin_bit_cast(frag_ab, bb);

        // A fragments: f32 -> bf16, then MFMA
        #pragma unroll
        for (int mt = 0; mt < 4; ++mt) {
            const frag_ab a = pack_bf16(a_c[mt][0], a_c[mt][1]);
            acc[mt] = __builtin_amdgcn_mfma_f32_16x16x32_bf16(a, b, acc[mt], 0, 0, 0);
        }
    }

    // ---- epilogue: C/D layout col = lane&15 (= n), row = q4*4 + r ----
    const float bf = bias[n];
    #pragma unroll
    for (int mt = 0; mt < 4; ++mt) {
        #pragma unroll
        for (int r = 0; r < 4; ++r) {
            const int m = mt * 16 + q4 * 4 + r;
            out[m * ND + n] = acc[mt][r] + bf;
        }
    }
}

extern "C" void kernel_launch(void* const* d_in, const int* in_sizes, int n_in,
                              void* d_out, int out_size, void* d_ws, size_t ws_size,
                              hipStream_t stream) {
    const float* x    = (const float*)d_in[0];
    const int*   qw   = (const int*)d_in[1];
    const float* sc   = (const float*)d_in[2];
    const int*   qz   = (const int*)d_in[3];
    const float* bias = (const float*)d_in[4];
    float*       out  = (float*)d_out;

    dim3 grid(ND / BN);   // 172 blocks
    awq_gemm<<<grid, 256, 0, stream>>>(x, qw, sc, qz, bias, out);
}

// Round 3
// 169.776 us; speedup vs baseline: 1.2573x; 1.2573x over previous
//
#include <hip/hip_runtime.h>

// AWQ int4 GEMM: out[64,11008](f32) = x[64,4096](f32) @ dequant(qweight) + bias
// qweight [K, N/8] int32 AWQ nibble order; qzeros [G, N/8] int32; scales [G, N] f32;
// group size 128 (G=32). Split-K=8 over blockIdx.y; out pre-initialized to bias,
// partial sums combined with global atomicAdd (f32, fire-and-forget).

#define KD   4096
#define ND   11008
#define NPW  1376      // ND/8
#define BN   64        // n-columns per block
#define KS   8         // split-K factor
#define KCH  (KD / KS) // 512 (= 4 quant groups, aligned)

using frag_ab = __attribute__((ext_vector_type(8))) short;   // 8 bf16 = 4 VGPR
using f32x4   = __attribute__((ext_vector_type(4))) float;
using bf16x8  = __attribute__((ext_vector_type(8))) __bf16;

__device__ __forceinline__ frag_ab pack_bf16(f32x4 a, f32x4 b) {
    bf16x8 r;
    r[0] = (__bf16)a[0]; r[1] = (__bf16)a[1]; r[2] = (__bf16)a[2]; r[3] = (__bf16)a[3];
    r[4] = (__bf16)b[0]; r[5] = (__bf16)b[1]; r[6] = (__bf16)b[2]; r[7] = (__bf16)b[3];
    return __builtin_bit_cast(frag_ab, r);
}

// out[m, n] = bias[n]   (ND = 43 * 256 exactly)
__global__ __launch_bounds__(256) void init_out(
    const float* __restrict__ bias, float* __restrict__ out)
{
    const int n = blockIdx.x * 256 + threadIdx.x;
    out[blockIdx.y * ND + n] = bias[n];
}

__global__ __launch_bounds__(256) void awq_gemm(
    const float* __restrict__ x,
    const int*   __restrict__ qw,
    const float* __restrict__ sc,
    const int*   __restrict__ qz,
    float*       __restrict__ out)
{
    const int tid  = threadIdx.x;
    const int wv   = tid >> 6;        // wave 0..3 -> n-tile
    const int lane = tid & 63;
    const int l15  = lane & 15;
    const int q4   = lane >> 4;       // quad 0..3

    // This lane's output/B column
    const int n   = blockIdx.x * BN + wv * 16 + l15;
    const int npw = n >> 3;
    // AWQ: logical col i within pack sits at nibble ((i&1)<<2)|(i>>1)
    const int sh  = ((((n & 1) << 2) | ((n & 7) >> 1)) << 2);

    const int k_start = blockIdx.y * KCH;
    const int k_end   = k_start + KCH;

    const int*   qwp = qw + npw;           // row k at qwp[k*NPW]
    const float* xp  = x + l15 * KD;       // + mt*16*KD + k

    f32x4 acc[4] = {};   // 4 m-tiles x 4 f32

    // ---- software-pipelined k loop (one step of prefetch) ----
    int   w_pf[8];
    f32x4 a_pf[4][2];
    {
        const int kb = k_start + q4 * 8;
        #pragma unroll
        for (int j = 0; j < 8; ++j) w_pf[j] = qwp[(kb + j) * NPW];
        #pragma unroll
        for (int mt = 0; mt < 4; ++mt) {
            a_pf[mt][0] = *(const f32x4*)(xp + mt * 16 * KD + kb);
            a_pf[mt][1] = *(const f32x4*)(xp + mt * 16 * KD + kb + 4);
        }
    }

    float s_f = 0.f, z_f = 0.f;
    for (int k0 = k_start; k0 < k_end; k0 += 32) {
        // group scale/zero (uniform branch; every 4th iteration)
        if ((k0 & 127) == 0) {
            const int g = k0 >> 7;
            s_f = sc[g * ND + n];
            const int z = (qz[g * NPW + npw] >> sh) & 0xF;
            z_f = -s_f * (float)z;    // exact in f32
        }

        // take current stage
        int   w_c[8];
        f32x4 a_c[4][2];
        #pragma unroll
        for (int j = 0; j < 8; ++j)  w_c[j] = w_pf[j];
        #pragma unroll
        for (int mt = 0; mt < 4; ++mt) {
            a_c[mt][0] = a_pf[mt][0];
            a_c[mt][1] = a_pf[mt][1];
        }

        // prefetch next k-step
        const int k1 = k0 + 32;
        if (k1 < k_end) {
            const int kb = k1 + q4 * 8;
            #pragma unroll
            for (int j = 0; j < 8; ++j) w_pf[j] = qwp[(kb + j) * NPW];
            #pragma unroll
            for (int mt = 0; mt < 4; ++mt) {
                a_pf[mt][0] = *(const f32x4*)(xp + mt * 16 * KD + kb);
                a_pf[mt][1] = *(const f32x4*)(xp + mt * 16 * KD + kb + 4);
            }
        }

        // dequant this lane's B fragment: 8 k-elements of column n
        // (q - z)*s == fma(q, s, -z*s), exact in f32, one RNE cvt to bf16
        bf16x8 bb;
        #pragma unroll
        for (int j = 0; j < 8; ++j) {
            const float f = fmaf((float)((w_c[j] >> sh) & 0xF), s_f, z_f);
            bb[j] = (__bf16)f;
        }
        const frag_ab b = __builtin_bit_cast(frag_ab, bb);

        // A fragments: f32 -> bf16, then MFMA
        #pragma unroll
        for (int mt = 0; mt < 4; ++mt) {
            const frag_ab a = pack_bf16(a_c[mt][0], a_c[mt][1]);
            acc[mt] = __builtin_amdgcn_mfma_f32_16x16x32_bf16(a, b, acc[mt], 0, 0, 0);
        }
    }

    // ---- epilogue: C/D layout col = lane&15 (= n), row = q4*4 + r ----
    #pragma unroll
    for (int mt = 0; mt < 4; ++mt) {
        #pragma unroll
        for (int r = 0; r < 4; ++r) {
            const int m = mt * 16 + q4 * 4 + r;
            atomicAdd(&out[m * ND + n], acc[mt][r]);
        }
    }
}

extern "C" void kernel_launch(void* const* d_in, const int* in_sizes, int n_in,
                              void* d_out, int out_size, void* d_ws, size_t ws_size,
                              hipStream_t stream) {
    const float* x    = (const float*)d_in[0];
    const int*   qw   = (const int*)d_in[1];
    const float* sc   = (const float*)d_in[2];
    const int*   qz   = (const int*)d_in[3];
    const float* bias = (const float*)d_in[4];
    float*       out  = (float*)d_out;

    init_out<<<dim3(ND / 256, 64), 256, 0, stream>>>(bias, out);
    awq_gemm<<<dim3(ND / BN, KS), 256, 0, stream>>>(x, qw, sc, qz, out);
}